// Round 4
// baseline (107.897 us; speedup 1.0000x reference)
//
#include <hip/hip_runtime.h>

#define IN_F 512
#define OUT_F 768
#define BD 256   // discrimination features
#define ID 16    // intermediate dim
#define ND 256   // batch
#define FCH 4    // K-split chunks
#define FLEN (IN_F / FCH)  // 128

// XOR-swizzled LDS float index for row r (0..1023), c4 in {0,4,8,12}.
// Spreads the 64B rows (stride 256B across lanes) over all banks.
__device__ __forceinline__ int swz(int r, int c4) {
    return (r * ID + c4) ^ (((r >> 2) & 7) << 2);
}

// grid 256 (b), block 1024 = (fc = t>>8, n = t&255). 16 waves/CU.
__global__ __launch_bounds__(1024) void mbd_fused(const float* __restrict__ x,
                                                  const float* __restrict__ T,
                                                  float* __restrict__ Mws,
                                                  float* __restrict__ out) {
    __shared__ float sh[1024 * ID];  // 64 KB
    const int b = blockIdx.x;
    const int t = threadIdx.x;
    const int fc = t >> 8;
    const int n = t & 255;

    // ---- phase A: partial projection over f-chunk [fc*128, fc*128+128) ----
    float acc[ID];
#pragma unroll
    for (int i = 0; i < ID; ++i) acc[i] = 0.f;

    const float4* xr = reinterpret_cast<const float4*>(x + (size_t)n * IN_F + fc * FLEN);
    const float* Tb = T + (size_t)b * ID + (size_t)(fc * FLEN) * (BD * ID);
    for (int f4 = 0; f4 < FLEN / 4; ++f4) {
        float4 xv = xr[f4];
        const float* t0 = Tb + (size_t)(4 * f4) * (BD * ID);  // uniform -> s_load
#pragma unroll
        for (int i = 0; i < ID; ++i) acc[i] = fmaf(xv.x, t0[i], acc[i]);
#pragma unroll
        for (int i = 0; i < ID; ++i) acc[i] = fmaf(xv.y, t0[BD * ID + i], acc[i]);
#pragma unroll
        for (int i = 0; i < ID; ++i) acc[i] = fmaf(xv.z, t0[2 * BD * ID + i], acc[i]);
#pragma unroll
        for (int i = 0; i < ID; ++i) acc[i] = fmaf(xv.w, t0[3 * BD * ID + i], acc[i]);
    }

    // ---- per-lane LDS write of partials (swizzled), cross-fc reduce ----
    {
        const int r = n * 4 + fc;
#pragma unroll
        for (int c = 0; c < 4; ++c)
            *reinterpret_cast<float4*>(&sh[swz(r, 4 * c)]) =
                make_float4(acc[4 * c], acc[4 * c + 1], acc[4 * c + 2], acc[4 * c + 3]);
    }
    __syncthreads();
    {
        // thread (fc,n) reduces i-range [fc*4, fc*4+4) across the 4 partial rows of n
        float4 s0 = *reinterpret_cast<const float4*>(&sh[swz(n * 4 + 0, fc * 4)]);
        float4 s1 = *reinterpret_cast<const float4*>(&sh[swz(n * 4 + 1, fc * 4)]);
        float4 s2 = *reinterpret_cast<const float4*>(&sh[swz(n * 4 + 2, fc * 4)]);
        float4 s3 = *reinterpret_cast<const float4*>(&sh[swz(n * 4 + 3, fc * 4)]);
        float4 r4 = make_float4(s0.x + s1.x + s2.x + s3.x, s0.y + s1.y + s2.y + s3.y,
                                s0.z + s1.z + s2.z + s3.z, s0.w + s1.w + s2.w + s3.w);
        *reinterpret_cast<float4*>(Mws + (size_t)b * (ND * ID) + n * ID + fc * 4) = r4;
    }
    __syncthreads();  // drains each wave's vmcnt -> M[b] visible in L2

    // ---- phase B: own row per-lane, mj via uniform s_load; j split by fc ----
    const float* Mb = Mws + (size_t)b * (ND * ID);
    float m[ID];
#pragma unroll
    for (int i = 0; i < ID; i += 4) {
        float4 v = *reinterpret_cast<const float4*>(Mb + (size_t)n * ID + i);
        m[i] = v.x; m[i + 1] = v.y; m[i + 2] = v.z; m[i + 3] = v.w;
    }
    float tot = 0.f;
    const int j0 = fc * (ND / FCH);
    for (int j = j0; j < j0 + ND / FCH; ++j) {
        const float* mj = Mb + (size_t)j * ID;  // uniform -> s_load
        float s0 = 0.f, s1 = 0.f, s2 = 0.f, s3 = 0.f;
#pragma unroll
        for (int i = 0; i < ID; i += 4) {
            s0 += fabsf(m[i + 0] - mj[i + 0]);
            s1 += fabsf(m[i + 1] - mj[i + 1]);
            s2 += fabsf(m[i + 2] - mj[i + 2]);
            s3 += fabsf(m[i + 3] - mj[i + 3]);
        }
        tot += __expf(-((s0 + s1) + (s2 + s3)));
    }
    sh[t] = tot;
    __syncthreads();

    if (t < ND) {
        float r = sh[t] + sh[t + 256] + sh[t + 512] + sh[t + 768] - 1.f;
        out[(size_t)t * OUT_F + IN_F + b] = r;
    }
    // concat: block b copies x row b -> out[b, 0:512]
    if (t < IN_F / 4) {
        const float4* xs = reinterpret_cast<const float4*>(x + (size_t)b * IN_F);
        reinterpret_cast<float4*>(out + (size_t)b * OUT_F)[t] = xs[t];
    }
}

// ---- fallback if ws too small: R1-style fused LDS kernel (known-good) ----
__global__ __launch_bounds__(256) void mbd_fallback(const float* __restrict__ x,
                                                    const float* __restrict__ T,
                                                    float* __restrict__ out) {
    __shared__ float Ml[ND * ID];
    const int b = blockIdx.x;
    const int n = threadIdx.x;
    float m[ID];
#pragma unroll
    for (int i = 0; i < ID; ++i) m[i] = 0.f;
    const float4* xr = reinterpret_cast<const float4*>(x + (size_t)n * IN_F);
    const float* Tb = T + (size_t)b * ID;
    for (int f4 = 0; f4 < IN_F / 4; ++f4) {
        float4 xv = xr[f4];
        const float* t0 = Tb + (size_t)(4 * f4) * (BD * ID);
#pragma unroll
        for (int i = 0; i < ID; ++i) m[i] = fmaf(xv.x, t0[i], m[i]);
#pragma unroll
        for (int i = 0; i < ID; ++i) m[i] = fmaf(xv.y, t0[BD * ID + i], m[i]);
#pragma unroll
        for (int i = 0; i < ID; ++i) m[i] = fmaf(xv.z, t0[2 * BD * ID + i], m[i]);
#pragma unroll
        for (int i = 0; i < ID; ++i) m[i] = fmaf(xv.w, t0[3 * BD * ID + i], m[i]);
    }
#pragma unroll
    for (int i = 0; i < ID; i += 4)
        *reinterpret_cast<float4*>(&Ml[n * ID + i]) = make_float4(m[i], m[i + 1], m[i + 2], m[i + 3]);
    __syncthreads();
    float tot = 0.f;
    for (int j = 0; j < ND; ++j) {
        const float* mj = &Ml[j * ID];
        float s0 = 0.f, s1 = 0.f, s2 = 0.f, s3 = 0.f;
#pragma unroll
        for (int i = 0; i < ID; i += 4) {
            s0 += fabsf(m[i + 0] - mj[i + 0]);
            s1 += fabsf(m[i + 1] - mj[i + 1]);
            s2 += fabsf(m[i + 2] - mj[i + 2]);
            s3 += fabsf(m[i + 3] - mj[i + 3]);
        }
        tot += __expf(-((s0 + s1) + (s2 + s3)));
    }
    out[(size_t)n * OUT_F + IN_F + b] = tot - 1.f;
    if (n < IN_F / 4) {
        const float4* xs = reinterpret_cast<const float4*>(x + (size_t)b * IN_F);
        reinterpret_cast<float4*>(out + (size_t)b * OUT_F)[n] = xs[n];
    }
}

extern "C" void kernel_launch(void* const* d_in, const int* in_sizes, int n_in,
                              void* d_out, int out_size, void* d_ws, size_t ws_size,
                              hipStream_t stream) {
    const float* x = (const float*)d_in[0];
    const float* T = (const float*)d_in[1];
    float* out = (float*)d_out;
    const size_t needed = (size_t)BD * ND * ID * sizeof(float);  // 4 MB

    if (ws_size >= needed) {
        mbd_fused<<<dim3(BD), dim3(1024), 0, stream>>>(x, T, (float*)d_ws, out);
    } else {
        mbd_fallback<<<dim3(BD), dim3(256), 0, stream>>>(x, T, out);
    }
}

// Round 5
// 95.496 us; speedup vs baseline: 1.1299x; 1.1299x over previous
//
#include <hip/hip_runtime.h>

#define IN_F 512
#define OUT_F 768
#define BD 256   // discrimination features
#define ID 16    // intermediate dim
#define ND 256   // batch
#define NT 16    // n-rows accumulated per thread (proj)

// ---------------- proj: M[b][n][i] = sum_f x[n,f] * T[f,b,i] --------------
// Column-stationary: thread owns column c=(b,i) (per-lane, coalesced T
// stream), 16 n-accumulators; x rows read via uniform s_load_dwordx4.
// grid = 64 c-groups x 4 n-groups = 256 blocks, 256 threads.
__global__ __launch_bounds__(256) void proj_kernel(const float* __restrict__ x,
                                                   const float* __restrict__ T,
                                                   float* __restrict__ M) {
    const int t = threadIdx.x;
    const int cg = blockIdx.x & 63;         // column group (64 cols each)
    const int ng = blockIdx.x >> 6;         // n group (64 rows each)
    const int c = cg * 64 + (t & 63);       // 0..4095, per-lane
    const int n0 = ng * 64 + (t >> 6) * NT; // uniform per wave

    float acc[NT];
#pragma unroll
    for (int k = 0; k < NT; ++k) acc[k] = 0.f;

    const float* Tc = T + c;  // T[f][c] = Tc[f*4096]

    float4 cur, nxt;
    cur.x = Tc[0 * 4096]; cur.y = Tc[1 * 4096];
    cur.z = Tc[2 * 4096]; cur.w = Tc[3 * 4096];

    for (int f = 0; f < IN_F - 4; f += 4) {
        const float* Tn = Tc + (size_t)(f + 4) * 4096;
        nxt.x = Tn[0]; nxt.y = Tn[1 * 4096]; nxt.z = Tn[2 * 4096]; nxt.w = Tn[3 * 4096];
#pragma unroll
        for (int k = 0; k < NT; ++k) {
            float4 xq = *reinterpret_cast<const float4*>(x + (size_t)(n0 + k) * IN_F + f);
            acc[k] = fmaf(xq.x, cur.x,
                     fmaf(xq.y, cur.y, fmaf(xq.z, cur.z, fmaf(xq.w, cur.w, acc[k]))));
        }
        cur = nxt;
    }
    {
        const int f = IN_F - 4;
#pragma unroll
        for (int k = 0; k < NT; ++k) {
            float4 xq = *reinterpret_cast<const float4*>(x + (size_t)(n0 + k) * IN_F + f);
            acc[k] = fmaf(xq.x, cur.x,
                     fmaf(xq.y, cur.y, fmaf(xq.z, cur.z, fmaf(xq.w, cur.w, acc[k]))));
        }
    }

    // store: M[b][n][i], c = b*16+i
    const int b = c >> 4, i = c & 15;
    float* Mb = M + (size_t)b * (ND * ID) + i;
#pragma unroll
    for (int k = 0; k < NT; ++k) Mb[(size_t)(n0 + k) * ID] = acc[k];
}

// ---------------- pair: out[n,512+b] = sum_j exp(-L1(m_n,m_j)) - 1 --------
// grid 256 (b), block 512: j-range split by wave-uniform sub (forced scalar
// via readfirstlane so mj loads stay s_load). Own row per-lane in VGPRs.
__global__ __launch_bounds__(512) void pair_kernel(const float* __restrict__ x,
                                                   const float* __restrict__ M,
                                                   float* __restrict__ out) {
    __shared__ float red[512];
    const int b = blockIdx.x;
    const int t = threadIdx.x;
    const int n = t & 255;
    const int sub = __builtin_amdgcn_readfirstlane(t >> 8);  // 0/1, SGPR
    const float* Mb = M + (size_t)b * (ND * ID);

    float m[ID];
#pragma unroll
    for (int i = 0; i < ID; i += 4) {
        float4 v = *reinterpret_cast<const float4*>(Mb + (size_t)n * ID + i);
        m[i] = v.x; m[i + 1] = v.y; m[i + 2] = v.z; m[i + 3] = v.w;
    }

    float tot = 0.f;
    const int j0 = sub * (ND / 2);
    for (int j = j0; j < j0 + ND / 2; ++j) {
        const float* mj = Mb + (size_t)j * ID;  // uniform -> s_load_dwordx16
        float s0 = 0.f, s1 = 0.f, s2 = 0.f, s3 = 0.f;
#pragma unroll
        for (int i = 0; i < ID; i += 4) {
            s0 += fabsf(m[i + 0] - mj[i + 0]);
            s1 += fabsf(m[i + 1] - mj[i + 1]);
            s2 += fabsf(m[i + 2] - mj[i + 2]);
            s3 += fabsf(m[i + 3] - mj[i + 3]);
        }
        tot += __expf(-((s0 + s1) + (s2 + s3)));
    }
    red[t] = tot;
    __syncthreads();

    if (t < 256) {
        out[(size_t)n * OUT_F + IN_F + b] = red[n] + red[n + 256] - 1.f;
    } else if (t < 256 + IN_F / 4) {
        // concat: copy x row b -> out[b, 0:512] (128 float4s)
        const int k = t - 256;
        const float4* xs = reinterpret_cast<const float4*>(x + (size_t)b * IN_F);
        reinterpret_cast<float4*>(out + (size_t)b * OUT_F)[k] = xs[k];
    }
}

// ---------------- fallback if ws too small: R1 fused (known-good 73us) ----
__global__ __launch_bounds__(256) void mbd_fallback(const float* __restrict__ x,
                                                    const float* __restrict__ T,
                                                    float* __restrict__ out) {
    __shared__ float Ml[ND * ID];
    const int b = blockIdx.x;
    const int n = threadIdx.x;
    float m[ID];
#pragma unroll
    for (int i = 0; i < ID; ++i) m[i] = 0.f;
    const float4* xr = reinterpret_cast<const float4*>(x + (size_t)n * IN_F);
    const float* Tb = T + (size_t)b * ID;
    for (int f4 = 0; f4 < IN_F / 4; ++f4) {
        float4 xv = xr[f4];
        const float* t0 = Tb + (size_t)(4 * f4) * (BD * ID);
#pragma unroll
        for (int i = 0; i < ID; ++i) m[i] = fmaf(xv.x, t0[i], m[i]);
#pragma unroll
        for (int i = 0; i < ID; ++i) m[i] = fmaf(xv.y, t0[BD * ID + i], m[i]);
#pragma unroll
        for (int i = 0; i < ID; ++i) m[i] = fmaf(xv.z, t0[2 * BD * ID + i], m[i]);
#pragma unroll
        for (int i = 0; i < ID; ++i) m[i] = fmaf(xv.w, t0[3 * BD * ID + i], m[i]);
    }
#pragma unroll
    for (int i = 0; i < ID; i += 4)
        *reinterpret_cast<float4*>(&Ml[n * ID + i]) =
            make_float4(m[i], m[i + 1], m[i + 2], m[i + 3]);
    __syncthreads();
    float tot = 0.f;
    for (int j = 0; j < ND; ++j) {
        const float* mj = &Ml[j * ID];
        float s0 = 0.f, s1 = 0.f, s2 = 0.f, s3 = 0.f;
#pragma unroll
        for (int i = 0; i < ID; i += 4) {
            s0 += fabsf(m[i + 0] - mj[i + 0]);
            s1 += fabsf(m[i + 1] - mj[i + 1]);
            s2 += fabsf(m[i + 2] - mj[i + 2]);
            s3 += fabsf(m[i + 3] - mj[i + 3]);
        }
        tot += __expf(-((s0 + s1) + (s2 + s3)));
    }
    out[(size_t)n * OUT_F + IN_F + b] = tot - 1.f;
    if (n < IN_F / 4) {
        const float4* xs = reinterpret_cast<const float4*>(x + (size_t)b * IN_F);
        reinterpret_cast<float4*>(out + (size_t)b * OUT_F)[n] = xs[n];
    }
}

extern "C" void kernel_launch(void* const* d_in, const int* in_sizes, int n_in,
                              void* d_out, int out_size, void* d_ws, size_t ws_size,
                              hipStream_t stream) {
    const float* x = (const float*)d_in[0];
    const float* T = (const float*)d_in[1];
    float* out = (float*)d_out;
    const size_t needed = (size_t)BD * ND * ID * sizeof(float);  // 4 MB

    if (ws_size >= needed) {
        float* M = (float*)d_ws;
        proj_kernel<<<dim3(256), dim3(256), 0, stream>>>(x, T, M);
        pair_kernel<<<dim3(BD), dim3(512), 0, stream>>>(x, M, out);
    } else {
        mbd_fallback<<<dim3(BD), dim3(256), 0, stream>>>(x, T, out);
    }
}

// Round 6
// 56.080 us; speedup vs baseline: 1.9240x; 1.7029x over previous
//
#include <hip/hip_runtime.h>
#include <stdint.h>

#define IN_F 512
#define OUT_F 768
#define BD 256
#define ID 16
#define ND 256
#define CD (BD * ID)  // 4096 projection columns

typedef __bf16 bf16x8 __attribute__((ext_vector_type(8)));
typedef float f32x4 __attribute__((ext_vector_type(4)));

__device__ __forceinline__ unsigned short f2bf(float f) {
    union { float f; uint32_t u; } v; v.f = f;
    uint32_t u = v.u + 0x7FFFu + ((v.u >> 16) & 1u);  // RNE
    return (unsigned short)(u >> 16);
}

// ---- prep: x -> xbf (row-major bf16); T -> Tt blocked [f>>3][c][f&7] bf16 ----
// blocks 0..2047: T (thread = one f, four consecutive c). blocks 2048..2111: x.
__global__ __launch_bounds__(256) void prep_kernel(const float* __restrict__ x,
                                                   const float* __restrict__ T,
                                                   unsigned short* __restrict__ Tt,
                                                   unsigned short* __restrict__ xbf) {
    const int bid = blockIdx.x;
    const int t = threadIdx.x;
    if (bid < 2048) {
        int gidx = bid * 256 + t;
        int f = gidx >> 10;              // 0..511
        int c = (gidx & 1023) * 4;       // 0..4092
        float4 v = *reinterpret_cast<const float4*>(T + (size_t)f * CD + c);
        unsigned short* base = Tt + (size_t)(f >> 3) * (CD * 8) + (f & 7);
        base[(size_t)(c + 0) * 8] = f2bf(v.x);
        base[(size_t)(c + 1) * 8] = f2bf(v.y);
        base[(size_t)(c + 2) * 8] = f2bf(v.z);
        base[(size_t)(c + 3) * 8] = f2bf(v.w);
    } else {
        int i0 = ((bid - 2048) * 256 + t) * 8;
        float4 a = *reinterpret_cast<const float4*>(x + i0);
        float4 b = *reinterpret_cast<const float4*>(x + i0 + 4);
        union { unsigned short s[8]; uint4 v; } u;
        u.s[0] = f2bf(a.x); u.s[1] = f2bf(a.y); u.s[2] = f2bf(a.z); u.s[3] = f2bf(a.w);
        u.s[4] = f2bf(b.x); u.s[5] = f2bf(b.y); u.s[6] = f2bf(b.z); u.s[7] = f2bf(b.w);
        *reinterpret_cast<uint4*>(xbf + i0) = u.v;
    }
}

// ---- gemm: M[b][n][i] = sum_f xbf[n,f] * T[f,(b,i)] via mfma 16x16x32 bf16 ----
// grid 1024 x 256thr (4 waves). Wave tile: rows n0..n0+15, cols c0..c0+15 (= feature b).
__global__ __launch_bounds__(256) void gemm_kernel(const unsigned short* __restrict__ xbf,
                                                   const unsigned short* __restrict__ Tt,
                                                   float* __restrict__ M) {
    const int t = threadIdx.x;
    const int lane = t & 63;
    const int w = t >> 6;
    const int nt = blockIdx.x & 15;      // n-tile 0..15
    const int ct4 = blockIdx.x >> 4;     // 0..63
    const int ctile = ct4 * 4 + w;       // 0..255 == feature b
    const int row = lane & 15;           // A row / D row base group
    const int g = lane >> 4;             // k-group 0..3
    const int col = lane & 15;           // B col = i

    const bf16x8* Av = reinterpret_cast<const bf16x8*>(xbf);
    const bf16x8* Bv = reinterpret_cast<const bf16x8*>(Tt);
    const int n0 = nt * 16;
    const int c = ctile * 16 + col;

    f32x4 acc = {0.f, 0.f, 0.f, 0.f};
    const int abase = (n0 + row) * (IN_F / 8) + g;  // + kk*4
    const int bbase = g * CD + c;                   // + kk*4*CD
#pragma unroll 4
    for (int kk = 0; kk < 16; ++kk) {
        bf16x8 av = Av[abase + kk * 4];
        bf16x8 bv = Bv[bbase + kk * 4 * CD];
        acc = __builtin_amdgcn_mfma_f32_16x16x32_bf16(av, bv, acc, 0, 0, 0);
    }
    // D: col = lane&15 (=i), row = g*4 + r  (m89-verified layout)
    float* Mo = M + (size_t)ctile * (ND * ID) + col;
#pragma unroll
    for (int r = 0; r < 4; ++r)
        Mo[(size_t)(n0 + g * 4 + r) * ID] = acc[r];
}

// ---- pair: partial[b,js][n] = sum_{j in js-quarter} exp(-L1(m_n, m_j)) ----
// grid 1024 = (b, js); js blockIdx-derived => provably uniform => mj s_loads.
__global__ __launch_bounds__(256) void pair_kernel(const float* __restrict__ M,
                                                   float* __restrict__ P) {
    const int js = blockIdx.x & 3;
    const int b = blockIdx.x >> 2;
    const int n = threadIdx.x;
    const float* Mb = M + (size_t)b * (ND * ID);

    float m[ID];
#pragma unroll
    for (int i = 0; i < ID; i += 4) {
        float4 v = *reinterpret_cast<const float4*>(Mb + (size_t)n * ID + i);
        m[i] = v.x; m[i + 1] = v.y; m[i + 2] = v.z; m[i + 3] = v.w;
    }
    float tot = 0.f;
    const int j0 = js * (ND / 4);
#pragma unroll 2
    for (int j = j0; j < j0 + ND / 4; ++j) {
        const float* mj = Mb + (size_t)j * ID;  // uniform -> s_load_dwordx16
        float s0 = 0.f, s1 = 0.f, s2 = 0.f, s3 = 0.f;
#pragma unroll
        for (int i = 0; i < ID; i += 4) {
            s0 += fabsf(m[i + 0] - mj[i + 0]);
            s1 += fabsf(m[i + 1] - mj[i + 1]);
            s2 += fabsf(m[i + 2] - mj[i + 2]);
            s3 += fabsf(m[i + 3] - mj[i + 3]);
        }
        tot += __expf(-((s0 + s1) + (s2 + s3)));
    }
    P[(size_t)(b * 4 + js) * ND + n] = tot;
}

// ---- reduce: out[n,512+b] = sum_js P - 1 ; plus x-concat copy ----
__global__ __launch_bounds__(256) void reduce_kernel(const float* __restrict__ P,
                                                     const float* __restrict__ x,
                                                     float* __restrict__ out) {
    const int b = blockIdx.x;
    const int n = threadIdx.x;
    float v = P[(size_t)(b * 4 + 0) * ND + n] + P[(size_t)(b * 4 + 1) * ND + n] +
              P[(size_t)(b * 4 + 2) * ND + n] + P[(size_t)(b * 4 + 3) * ND + n] - 1.f;
    out[(size_t)n * OUT_F + IN_F + b] = v;
    if (n < IN_F / 4) {
        float4 xv = reinterpret_cast<const float4*>(x + (size_t)b * IN_F)[n];
        reinterpret_cast<float4*>(out + (size_t)b * OUT_F)[n] = xv;
    }
}

// ---- fallback (ws too small): R1 fused kernel (known-good ~74us) ----
__global__ __launch_bounds__(256) void mbd_fallback(const float* __restrict__ x,
                                                    const float* __restrict__ T,
                                                    float* __restrict__ out) {
    __shared__ float Ml[ND * ID];
    const int b = blockIdx.x;
    const int n = threadIdx.x;
    float m[ID];
#pragma unroll
    for (int i = 0; i < ID; ++i) m[i] = 0.f;
    const float4* xr = reinterpret_cast<const float4*>(x + (size_t)n * IN_F);
    const float* Tb = T + (size_t)b * ID;
    for (int f4 = 0; f4 < IN_F / 4; ++f4) {
        float4 xv = xr[f4];
        const float* t0 = Tb + (size_t)(4 * f4) * CD;
#pragma unroll
        for (int i = 0; i < ID; ++i) m[i] = fmaf(xv.x, t0[i], m[i]);
#pragma unroll
        for (int i = 0; i < ID; ++i) m[i] = fmaf(xv.y, t0[CD + i], m[i]);
#pragma unroll
        for (int i = 0; i < ID; ++i) m[i] = fmaf(xv.z, t0[2 * CD + i], m[i]);
#pragma unroll
        for (int i = 0; i < ID; ++i) m[i] = fmaf(xv.w, t0[3 * CD + i], m[i]);
    }
#pragma unroll
    for (int i = 0; i < ID; i += 4)
        *reinterpret_cast<float4*>(&Ml[n * ID + i]) =
            make_float4(m[i], m[i + 1], m[i + 2], m[i + 3]);
    __syncthreads();
    float tot = 0.f;
    for (int j = 0; j < ND; ++j) {
        const float* mj = &Ml[j * ID];
        float s0 = 0.f, s1 = 0.f, s2 = 0.f, s3 = 0.f;
#pragma unroll
        for (int i = 0; i < ID; i += 4) {
            s0 += fabsf(m[i + 0] - mj[i + 0]);
            s1 += fabsf(m[i + 1] - mj[i + 1]);
            s2 += fabsf(m[i + 2] - mj[i + 2]);
            s3 += fabsf(m[i + 3] - mj[i + 3]);
        }
        tot += __expf(-((s0 + s1) + (s2 + s3)));
    }
    out[(size_t)n * OUT_F + IN_F + b] = tot - 1.f;
    if (n < IN_F / 4) {
        const float4* xs = reinterpret_cast<const float4*>(x + (size_t)b * IN_F);
        reinterpret_cast<float4*>(out + (size_t)b * OUT_F)[n] = xs[n];
    }
}

extern "C" void kernel_launch(void* const* d_in, const int* in_sizes, int n_in,
                              void* d_out, int out_size, void* d_ws, size_t ws_size,
                              hipStream_t stream) {
    const float* x = (const float*)d_in[0];
    const float* T = (const float*)d_in[1];
    float* out = (float*)d_out;

    // ws layout (bytes): Tt bf16 @0 (4 MB) | xbf bf16 @4 MB (256 KB) |
    //                    M f32 @4.25 MB (4 MB) | P f32 @8.25 MB (1 MB)
    const size_t off_xbf = 4194304;
    const size_t off_M = off_xbf + 262144;
    const size_t off_P = off_M + 4194304;
    const size_t needed = off_P + 1048576;  // 9,699,328 B

    if (ws_size >= needed) {
        unsigned short* Tt = (unsigned short*)d_ws;
        unsigned short* xbf = (unsigned short*)((char*)d_ws + off_xbf);
        float* M = (float*)((char*)d_ws + off_M);
        float* P = (float*)((char*)d_ws + off_P);
        prep_kernel<<<dim3(2112), dim3(256), 0, stream>>>(x, T, Tt, xbf);
        gemm_kernel<<<dim3(1024), dim3(256), 0, stream>>>(xbf, Tt, M);
        pair_kernel<<<dim3(1024), dim3(256), 0, stream>>>(M, P);
        reduce_kernel<<<dim3(256), dim3(256), 0, stream>>>(P, x, out);
    } else {
        mbd_fallback<<<dim3(BD), dim3(256), 0, stream>>>(x, T, out);
    }
}